// Round 1
// baseline (466.876 us; speedup 1.0000x reference)
//
#include <hip/hip_runtime.h>

#define K_IN 256
#define N_OUT 64

// ---------------- GEMM: XW = X @ W  (fp32 vector, 64x64 tile, 4x4/thread) ---
__global__ __launch_bounds__(256) void gemm_xw(const float* __restrict__ X,
                                               const float* __restrict__ W,
                                               float* __restrict__ XW, int n) {
  __shared__ float Xs[64][68];  // [row][k], pad 68 keeps float4 16B-aligned, banks ok
  __shared__ float Ws[64][68];  // [k][col]
  const int tid = threadIdx.x;
  const int row0 = blockIdx.x * 64;
  const int tx = tid & 15;   // col group: cols 4*tx..4*tx+3
  const int ty = tid >> 4;   // row group: rows 4*ty..4*ty+3
  float acc[4][4] = {};
  for (int kc = 0; kc < K_IN; kc += 64) {
#pragma unroll
    for (int i = 0; i < 4; ++i) {
      int flat = tid + i * 256;     // 0..1023
      int r = flat >> 4;            // 0..63
      int q = flat & 15;            // 0..15
      int gr = row0 + r; if (gr >= n) gr = n - 1;
      float4 xv = *reinterpret_cast<const float4*>(&X[(size_t)gr * K_IN + kc + q * 4]);
      *reinterpret_cast<float4*>(&Xs[r][q * 4]) = xv;
      float4 wv = *reinterpret_cast<const float4*>(&W[(size_t)(kc + r) * N_OUT + q * 4]);
      *reinterpret_cast<float4*>(&Ws[r][q * 4]) = wv;
    }
    __syncthreads();
#pragma unroll
    for (int k = 0; k < 64; ++k) {
      float4 wv = *reinterpret_cast<const float4*>(&Ws[k][tx * 4]);
#pragma unroll
      for (int i = 0; i < 4; ++i) {
        float xv = Xs[ty * 4 + i][k];
        acc[i][0] += xv * wv.x;
        acc[i][1] += xv * wv.y;
        acc[i][2] += xv * wv.z;
        acc[i][3] += xv * wv.w;
      }
    }
    __syncthreads();
  }
#pragma unroll
  for (int i = 0; i < 4; ++i) {
    int gr = row0 + ty * 4 + i;
    if (gr < n) {
      float4 o = make_float4(acc[i][0], acc[i][1], acc[i][2], acc[i][3]);
      *reinterpret_cast<float4*>(&XW[(size_t)gr * N_OUT + tx * 4]) = o;
    }
  }
}

// ---------------- CSR build ----------------
__global__ void hist_rows(const int* __restrict__ er, int* __restrict__ cnt, int E) {
  int i = blockIdx.x * blockDim.x + threadIdx.x;
  if (i < E) atomicAdd(&cnt[er[i]], 1);
}

// exclusive scan, 1024 elements per block (256 thr x 4)
__global__ void scan_blocks(const int* __restrict__ cnt, int* __restrict__ offs,
                            int* __restrict__ partials, int n) {
  __shared__ int sd[2][256];
  int tid = threadIdx.x;
  int base = blockIdx.x * 1024 + tid * 4;
  int v[4]; int s = 0;
#pragma unroll
  for (int i = 0; i < 4; ++i) {
    int idx = base + i;
    int c = (idx < n) ? cnt[idx] : 0;
    v[i] = s; s += c;
  }
  int buf = 0; sd[0][tid] = s; __syncthreads();
#pragma unroll
  for (int d = 1; d < 256; d <<= 1) {
    int x = sd[buf][tid];
    if (tid >= d) x += sd[buf][tid - d];
    sd[buf ^ 1][tid] = x; buf ^= 1; __syncthreads();
  }
  int texcl = (tid > 0) ? sd[buf][tid - 1] : 0;
  if (tid == 255) partials[blockIdx.x] = sd[buf][255];
#pragma unroll
  for (int i = 0; i < 4; ++i) {
    int idx = base + i;
    if (idx < n) offs[idx] = texcl + v[i];
  }
}

// single-block exclusive scan of up to 1024 partials
__global__ void scan_single(const int* __restrict__ in, int* __restrict__ outp, int n) {
  __shared__ int sd[2][256];
  int tid = threadIdx.x;
  int base = tid * 4;
  int v[4]; int s = 0;
#pragma unroll
  for (int i = 0; i < 4; ++i) {
    int idx = base + i;
    int c = (idx < n) ? in[idx] : 0;
    v[i] = s; s += c;
  }
  int buf = 0; sd[0][tid] = s; __syncthreads();
#pragma unroll
  for (int d = 1; d < 256; d <<= 1) {
    int x = sd[buf][tid];
    if (tid >= d) x += sd[buf][tid - d];
    sd[buf ^ 1][tid] = x; buf ^= 1; __syncthreads();
  }
  int texcl = (tid > 0) ? sd[buf][tid - 1] : 0;
#pragma unroll
  for (int i = 0; i < 4; ++i) {
    int idx = base + i;
    if (idx < n) outp[idx] = texcl + v[i];
  }
}

__global__ void finalize_offs(int* __restrict__ offs, int* __restrict__ wp,
                              const int* __restrict__ pp, int n, int E) {
  int i = blockIdx.x * blockDim.x + threadIdx.x;
  if (i < n) {
    int v = offs[i] + pp[i >> 10];
    offs[i] = v; wp[i] = v;
  } else if (i == n) {
    offs[n] = E;
  }
}

__global__ void scatter_edges(const int* __restrict__ er, const int* __restrict__ ec,
                              const float* __restrict__ ev, int* __restrict__ wp,
                              int* __restrict__ ccol, float* __restrict__ cval, int E) {
  int e = blockIdx.x * blockDim.x + threadIdx.x;
  if (e >= E) return;
  int r = er[e];
  int p = atomicAdd(&wp[r], 1);
  ccol[p] = ec[e];
  cval[p] = ev[e];
}

// ---------------- gather SpMM + bias + ReLU: wave per row, lane = feature ---
__global__ __launch_bounds__(256) void spmm_rows(const int* __restrict__ offs,
    const int* __restrict__ ccol, const float* __restrict__ cval,
    const float* __restrict__ xw, const float* __restrict__ bias,
    float* __restrict__ out, int n) {
  int wid = (int)((blockIdx.x * blockDim.x + threadIdx.x) >> 6);
  int lane = threadIdx.x & 63;
  if (wid >= n) return;
  int start = offs[wid], end = offs[wid + 1];
  float acc = 0.f;
  for (int e0 = start; e0 < end; e0 += 64) {
    int m = end - e0; if (m > 64) m = 64;
    int c = 0; float v = 0.f;
    if (lane < m) { c = ccol[e0 + lane]; v = cval[e0 + lane]; }
    for (int i = 0; i < m; ++i) {
      int ci = __shfl(c, i);
      float vi = __shfl(v, i);
      acc += vi * xw[(size_t)ci * N_OUT + lane];
    }
  }
  out[(size_t)wid * N_OUT + lane] = fmaxf(acc + bias[lane], 0.f);
}

// ---------------- atomic fallback (if ws too small for CSR) ----------------
__global__ void spmm_atomic(const int* __restrict__ er, const int* __restrict__ ec,
                            const float* __restrict__ ev, const float* __restrict__ xw,
                            float* __restrict__ out, int E) {
  int wid = (int)((blockIdx.x * blockDim.x + threadIdx.x) >> 6);
  int lane = threadIdx.x & 63;
  if (wid >= E) return;
  int r = er[wid], c = ec[wid];
  float v = ev[wid];
  atomicAdd(&out[(size_t)r * N_OUT + lane], v * xw[(size_t)c * N_OUT + lane]);
}

__global__ void bias_relu(float* __restrict__ out, const float* __restrict__ bias, int total) {
  int i = blockIdx.x * blockDim.x + threadIdx.x;
  if (i < total) out[i] = fmaxf(out[i] + bias[i & (N_OUT - 1)], 0.f);
}

extern "C" void kernel_launch(void* const* d_in, const int* in_sizes, int n_in,
                              void* d_out, int out_size, void* d_ws, size_t ws_size,
                              hipStream_t stream) {
  const float* X    = (const float*)d_in[0];
  const int*   er   = (const int*)d_in[1];
  const int*   ec   = (const int*)d_in[2];
  const float* ev   = (const float*)d_in[3];
  const float* W    = (const float*)d_in[4];
  const float* bias = (const float*)d_in[5];
  const int n = in_sizes[0] / K_IN;
  const int E = in_sizes[1];
  float* out = (float*)d_out;

  auto rnd = [](size_t b) { return (b + 255) & ~(size_t)255; };
  const size_t sz_xw   = rnd((size_t)n * N_OUT * 4);
  const size_t sz_cnt  = rnd((size_t)n * 4);
  const size_t sz_offs = rnd(((size_t)n + 1) * 4);
  const size_t sz_wp   = sz_cnt;
  const int nb_scan = (n + 1023) / 1024;
  const size_t sz_part = rnd((size_t)nb_scan * 4);
  const size_t sz_col  = rnd((size_t)E * 4);
  const size_t sz_val  = rnd((size_t)E * 4);
  const size_t need = sz_xw + sz_cnt + sz_offs + sz_wp + 2 * sz_part + sz_col + sz_val;

  char* ws = (char*)d_ws;
  float* xw = (float*)ws; ws += sz_xw;

  // 1) GEMM
  gemm_xw<<<(n + 63) / 64, 256, 0, stream>>>(X, W, xw, n);

  if (ws_size >= need && nb_scan <= 1024) {
    int*   cnt   = (int*)ws;   ws += sz_cnt;
    int*   offs  = (int*)ws;   ws += sz_offs;
    int*   wp    = (int*)ws;   ws += sz_wp;
    int*   part  = (int*)ws;   ws += sz_part;
    int*   pp    = (int*)ws;   ws += sz_part;
    int*   ccol  = (int*)ws;   ws += sz_col;
    float* cval  = (float*)ws; ws += sz_val;

    hipMemsetAsync(cnt, 0, (size_t)n * 4, stream);
    hist_rows<<<(E + 255) / 256, 256, 0, stream>>>(er, cnt, E);
    scan_blocks<<<nb_scan, 256, 0, stream>>>(cnt, offs, part, n);
    scan_single<<<1, 256, 0, stream>>>(part, pp, nb_scan);
    finalize_offs<<<(n + 1 + 255) / 256, 256, 0, stream>>>(offs, wp, pp, n, E);
    scatter_edges<<<(E + 255) / 256, 256, 0, stream>>>(er, ec, ev, wp, ccol, cval, E);
    spmm_rows<<<(n + 3) / 4, 256, 0, stream>>>(offs, ccol, cval, xw, bias, out, n);
  } else {
    // fallback: atomic scatter
    hipMemsetAsync(out, 0, (size_t)n * N_OUT * 4, stream);
    spmm_atomic<<<(E + 3) / 4, 256, 0, stream>>>(er, ec, ev, xw, out, E);
    bias_relu<<<(n * N_OUT + 255) / 256, 256, 0, stream>>>(out, bias, n * N_OUT);
  }
}